// Round 10
// baseline (2338.999 us; speedup 1.0000x reference)
//
#include <hip/hip_runtime.h>
#include <hip/hip_cooperative_groups.h>

namespace cg = cooperative_groups;

#define NN 100000
#define NE 3200000
#define NB 1021        // buckets
#define BNODES 98      // nodes per bucket (98*1021 >= NN)
#define NBLK 256       // partition blocks
#define CH 12500       // edges per partition block (NBLK*CH == NE)
#define NCHUNK 8       // src chunks (12500 nodes, 3.2MB bf16 slice @128ch)
#define AGG_BLOCKS 512 // 2 blocks/CU -- far below co-residency limit

typedef unsigned int uint;

// ---- bf16 helpers (RTNE) ----
__device__ inline uint bfr(float f) {
  uint u = __float_as_uint(f);
  return (u + 0x7fffu + ((u >> 16) & 1u)) >> 16;
}
__device__ inline uint packbf(float a, float b) { return bfr(a) | (bfr(b) << 16); }
__device__ inline void addq(uint4 q, float* a) {
  uint u[4] = {q.x, q.y, q.z, q.w};
#pragma unroll
  for (int j = 0; j < 4; ++j) {
    a[2 * j]     += __uint_as_float(u[j] << 16);
    a[2 * j + 1] += __uint_as_float(u[j] & 0xffff0000u);
  }
}
// chunk = s / 12500 via magic multiply (exact for s < 2^17)
__device__ inline int chunk8(int s) {
  return (int)(((unsigned long long)(uint)s * 343598ull) >> 32);
}

// ---------------- P1: per-block bucket histogram ----------------
__global__ __launch_bounds__(256) void pcount_kernel(const int* __restrict__ dst,
                                                     int* __restrict__ cntmat) {
  __shared__ int cnt[NB];
  int bk = blockIdx.x, tid = threadIdx.x;
  for (int j = tid; j < NB; j += 256) cnt[j] = 0;
  __syncthreads();
  int base = bk * CH;
  for (int i = base + tid * 4; i < base + CH; i += 1024) {
    int4 d4 = *(const int4*)&dst[i];
    atomicAdd(&cnt[(uint)d4.x / (uint)BNODES], 1);
    atomicAdd(&cnt[(uint)d4.y / (uint)BNODES], 1);
    atomicAdd(&cnt[(uint)d4.z / (uint)BNODES], 1);
    atomicAdd(&cnt[(uint)d4.w / (uint)BNODES], 1);
  }
  __syncthreads();
  for (int j = tid; j < NB; j += 256) cntmat[(size_t)j * NBLK + bk] = cnt[j];
}

// ---------------- P2a: bucket totals ----------------
__global__ __launch_bounds__(256) void rowsum_kernel(const int* __restrict__ cntmat,
                                                     int* __restrict__ btotal) {
  int b = blockIdx.x, t = threadIdx.x;
  int v = cntmat[(size_t)b * NBLK + t];
#pragma unroll
  for (int off = 32; off >= 1; off >>= 1) v += __shfl_xor(v, off, 64);
  __shared__ int ws[4];
  if ((t & 63) == 0) ws[t >> 6] = v;
  __syncthreads();
  if (t == 0) btotal[b] = ws[0] + ws[1] + ws[2] + ws[3];
}

// ---------------- P2b: scan bucket totals -> bases ----------------
__global__ __launch_bounds__(1024) void bucket_scan_kernel(const int* __restrict__ btotal,
                                                           int* __restrict__ bbase) {
  __shared__ int sh[1024];
  int i = threadIdx.x;
  int v = (i < NB) ? btotal[i] : 0;
  sh[i] = v;
  __syncthreads();
  for (int off = 1; off < 1024; off <<= 1) {
    int t = (i >= off) ? sh[i - off] : 0;
    __syncthreads();
    sh[i] += t;
    __syncthreads();
  }
  if (i < NB) bbase[i] = sh[i] - v;
}

// ---------------- P2c: per-(bucket,block) offsets ----------------
__global__ __launch_bounds__(256) void offsets_kernel(const int* __restrict__ cntmat,
                                                      const int* __restrict__ bbase,
                                                      int* __restrict__ offmat) {
  __shared__ int sh[256];
  int b = blockIdx.x, t = threadIdx.x;
  int v = cntmat[(size_t)b * NBLK + t];
  sh[t] = v;
  __syncthreads();
  for (int off = 1; off < 256; off <<= 1) {
    int u = (t >= off) ? sh[t - off] : 0;
    __syncthreads();
    sh[t] += u;
    __syncthreads();
  }
  offmat[(size_t)b * NBLK + t] = bbase[b] + sh[t] - v;
}

// ---------------- P3: scatter into bucket-contiguous store (packed 4B) ----------------
__global__ __launch_bounds__(256) void pscatter_kernel(const int* __restrict__ src,
                                                       const int* __restrict__ dst,
                                                       const int* __restrict__ offmat,
                                                       int* __restrict__ store) {
  __shared__ int lcur[NB];
  int bk = blockIdx.x, tid = threadIdx.x;
  for (int j = tid; j < NB; j += 256) lcur[j] = offmat[(size_t)j * NBLK + bk];
  __syncthreads();
  int base = bk * CH;
  for (int i = base + tid * 4; i < base + CH; i += 1024) {
    int4 d4 = *(const int4*)&dst[i];
    int4 s4 = *(const int4*)&src[i];
    int dd[4] = {d4.x, d4.y, d4.z, d4.w};
    int ss[4] = {s4.x, s4.y, s4.z, s4.w};
#pragma unroll
    for (int j = 0; j < 4; ++j) {
      uint b = (uint)dd[j] / (uint)BNODES;
      int dl = dd[j] - (int)(b * BNODES);
      int pos = atomicAdd(&lcur[b], 1);
      store[pos] = ss[j] | (dl << 17);
    }
  }
}

// ---------------- P4: per-bucket chunk-major CSR + packed rcp + dinv ----------------
// bin = c*BNODES + dl; rcp[node*8+c] = (abs_start<<8)|len
__global__ __launch_bounds__(256) void build_kernel(const int* __restrict__ btotal,
                                                    const int* __restrict__ bbase,
                                                    const int* __restrict__ store,
                                                    int* __restrict__ rcp,
                                                    float* __restrict__ dinv,
                                                    int* __restrict__ csr_src) {
  __shared__ int cnt2[NCHUNK * BNODES];
  __shared__ int excl2[NCHUNK * BNODES];
  int b = blockIdx.x, tid = threadIdx.x;
  int nb0 = b * BNODES;
  int nn = min(BNODES, NN - nb0);
  for (int j = tid; j < NCHUNK * BNODES; j += 256) cnt2[j] = 0;
  __syncthreads();
  int sz = btotal[b], bb = bbase[b];
  const int* bs = store + bb;
  for (int e = tid; e < sz; e += 256) {
    int p = bs[e];
    int dl = (int)((uint)p >> 17);
    int s = p & 0x1FFFF;
    atomicAdd(&cnt2[chunk8(s) * BNODES + dl], 1);
  }
  __syncthreads();
  if (tid == 0) {
    int run = 0;
    for (int j = 0; j < NCHUNK * BNODES; ++j) { excl2[j] = run; run += cnt2[j]; }
  }
  __syncthreads();
  for (int j = tid; j < nn; j += 256) {
    int deg = 0;
#pragma unroll
    for (int c = 0; c < NCHUNK; ++c) {
      int bin = c * BNODES + j;
      int st = bb + excl2[bin];
      int ln = cnt2[bin];
      rcp[(size_t)(nb0 + j) * 8 + c] = (st << 8) | ln;
      deg += ln;
    }
    dinv[nb0 + j] = rsqrtf((float)(deg + 1));
  }
  __syncthreads();
  for (int j = tid; j < NCHUNK * BNODES; j += 256) cnt2[j] = 0;  // cursors
  __syncthreads();
  for (int e = tid; e < sz; e += 256) {
    int p = bs[e];
    int dl = (int)((uint)p >> 17);
    int s = p & 0x1FFFF;
    int bin = chunk8(s) * BNODES + dl;
    int pos = atomicAdd(&cnt2[bin], 1);
    csr_src[bb + excl2[bin] + pos] = s;
  }
}

// ---- GEMM: C[M][N](bf16) = (X[M][128] @ W[128][N]) * dinv[row]; X fp32 or bf16 ----
template <int N, bool INBF>
__global__ __launch_bounds__(512) void gemm_kernel(const void* __restrict__ Xv,
                                                   const float* __restrict__ W,
                                                   const float* __restrict__ dinv,
                                                   ushort* __restrict__ C, int M) {
  constexpr int BM = 128, BN = 64, BK = 32, K = 128;
  __shared__ float XsT[BK][BM + 4];
  __shared__ float Ws[BK][BN];
  int tid = threadIdx.x;
  int row0 = blockIdx.x * BM;
  int col0 = blockIdx.y * BN;
  int tx = tid & 15;
  int ty = tid >> 4;

  float acc[4][4];
#pragma unroll
  for (int i = 0; i < 4; ++i)
#pragma unroll
    for (int j = 0; j < 4; ++j) acc[i][j] = 0.f;

  for (int k0 = 0; k0 < K; k0 += BK) {
    {
      int r = tid >> 4;
      int c4 = (tid & 15) * 4;
      *(float4*)&Ws[r][c4] = *(const float4*)&W[(size_t)(k0 + r) * N + col0 + c4];
    }
    if (INBF) {
      const ushort* Xb = (const ushort*)Xv;
      int r = tid >> 2;
      int c0 = (tid & 3) * 8;
      uint4 v = make_uint4(0, 0, 0, 0);
      if (row0 + r < M) v = *(const uint4*)&Xb[(size_t)(row0 + r) * K + k0 + c0];
      uint u[4] = {v.x, v.y, v.z, v.w};
#pragma unroll
      for (int j = 0; j < 4; ++j) {
        XsT[c0 + 2 * j][r]     = __uint_as_float(u[j] << 16);
        XsT[c0 + 2 * j + 1][r] = __uint_as_float(u[j] & 0xffff0000u);
      }
    } else {
      const float* Xf = (const float*)Xv;
#pragma unroll
      for (int i = 0; i < 2; ++i) {
        int idx = tid + i * 512;
        int r = idx >> 3;
        int c = (idx & 7) * 4;
        float4 v = make_float4(0.f, 0.f, 0.f, 0.f);
        if (row0 + r < M) v = *(const float4*)&Xf[(size_t)(row0 + r) * K + k0 + c];
        XsT[c + 0][r] = v.x;
        XsT[c + 1][r] = v.y;
        XsT[c + 2][r] = v.z;
        XsT[c + 3][r] = v.w;
      }
    }
    __syncthreads();

#pragma unroll
    for (int kk = 0; kk < BK; ++kk) {
      float4 a = *(float4*)&XsT[kk][ty * 4];
      float4 b = *(float4*)&Ws[kk][tx * 4];
      float av[4] = {a.x, a.y, a.z, a.w};
      float bv[4] = {b.x, b.y, b.z, b.w};
#pragma unroll
      for (int i = 0; i < 4; ++i)
#pragma unroll
        for (int j = 0; j < 4; ++j) acc[i][j] = fmaf(av[i], bv[j], acc[i][j]);
    }
    __syncthreads();
  }

#pragma unroll
  for (int i = 0; i < 4; ++i) {
    int row = row0 + ty * 4 + i;
    if (row < M) {
      float s = dinv[row];
      uint2 st;
      st.x = packbf(acc[i][0] * s, acc[i][1] * s);
      st.y = packbf(acc[i][2] * s, acc[i][3] * s);
      *(uint2*)&C[(size_t)row * N + col0 + tx * 4] = st;
    }
  }
}

// ---- chunk-synchronized persistent aggregation ----
// MODE 0: H bf16 [n,128] + relu.  MODE 1: H fp32 [n,64] + fused out-linear.
// COOP: grid.sync() between chunk phases (perf-only; correctness identical without).
template <int LPN, int ROUNDS, int MODE, bool COOP>
__global__ __launch_bounds__(256, 2) void agg_chunked_kernel(
    const uint4* __restrict__ Tq, const int* __restrict__ rcp,
    const int* __restrict__ csr_src, const float* __restrict__ dinv,
    const float* __restrict__ bias, void* __restrict__ Hv,
    const float* __restrict__ Wout, const float* __restrict__ bout,
    float* __restrict__ Out, int n) {
  constexpr int SPB = 256 / LPN;
  const int SLOTS = AGG_BLOCKS * SPB;
  int lane = threadIdx.x & (LPN - 1);
  int slot0 = blockIdx.x * SPB + (int)(threadIdx.x / LPN);

  float acc[ROUNDS][8];
#pragma unroll
  for (int r = 0; r < ROUNDS; ++r)
#pragma unroll
    for (int j = 0; j < 8; ++j) acc[r][j] = 0.f;

  for (int c = 0; c < NCHUNK; ++c) {
#pragma unroll
    for (int r = 0; r < ROUNDS; ++r) {
      int node = slot0 + r * SLOTS;
      if (node < n) {
        int v = rcp[(size_t)node * 8 + c];
        int lo = v >> 8;
        int hi = lo + (v & 255);
        if (chunk8(node) == c) addq(Tq[(size_t)node * LPN + lane], acc[r]);
        int e = lo;
        for (; e + 2 <= hi; e += 2) {
          int s0 = csr_src[e], s1 = csr_src[e + 1];
          uint4 q0 = Tq[(size_t)s0 * LPN + lane];
          uint4 q1 = Tq[(size_t)s1 * LPN + lane];
          addq(q0, acc[r]);
          addq(q1, acc[r]);
        }
        if (e < hi) addq(Tq[(size_t)csr_src[e] * LPN + lane], acc[r]);
      }
    }
    if (COOP) {
      if (c + 1 < NCHUNK) cg::this_grid().sync();
    }
  }

#pragma unroll
  for (int r = 0; r < ROUNDS; ++r) {
    int node = slot0 + r * SLOTS;
    if (node >= n) continue;
    float dn = dinv[node];
    float4 bv0 = *(const float4*)&bias[lane * 8];
    float4 bv1 = *(const float4*)&bias[lane * 8 + 4];
    float bb[8] = {bv0.x, bv0.y, bv0.z, bv0.w, bv1.x, bv1.y, bv1.z, bv1.w};
    float h[8];
#pragma unroll
    for (int j = 0; j < 8; ++j) h[j] = fmaf(dn, acc[r][j], bb[j]);
    if (MODE == 0) {
#pragma unroll
      for (int j = 0; j < 8; ++j) h[j] = fmaxf(h[j], 0.f);
      ushort* Hb = (ushort*)Hv;
      uint4 st;
      st.x = packbf(h[0], h[1]);
      st.y = packbf(h[2], h[3]);
      st.z = packbf(h[4], h[5]);
      st.w = packbf(h[6], h[7]);
      *(uint4*)&Hb[(size_t)node * 128 + lane * 8] = st;
    } else {
      float* Hf = (float*)Hv;
      float* Hrow = &Hf[(size_t)node * 64 + lane * 8];
      *(float4*)&Hrow[0] = make_float4(h[0], h[1], h[2], h[3]);
      *(float4*)&Hrow[4] = make_float4(h[4], h[5], h[6], h[7]);
      int k0 = 8 * lane;
      float p0 = 0.f, p1 = 0.f;
#pragma unroll
      for (int j = 0; j < 8; ++j) {
        p0 = fmaf(h[j], Wout[(k0 + j) * 2 + 0], p0);
        p1 = fmaf(h[j], Wout[(k0 + j) * 2 + 1], p1);
      }
#pragma unroll
      for (int off = 4; off >= 1; off >>= 1) {
        p0 += __shfl_xor(p0, off, 8);
        p1 += __shfl_xor(p1, off, 8);
      }
      if (lane == 0) {
        Out[(size_t)node * 2 + 0] = p0 + bout[0];
        Out[(size_t)node * 2 + 1] = p1 + bout[1];
      }
    }
  }
}

// launch helper: try cooperative, fall back to plain launch of COOP=false variant
template <int LPN, int ROUNDS, int MODE>
static void launch_agg(const uint4* Tq, const int* rcp, const int* csr_src,
                       const float* dinv, const float* bias, void* Hv,
                       const float* Wout, const float* bout, float* Out, int n,
                       hipStream_t stream) {
  const uint4* a0 = Tq; const int* a1 = rcp; const int* a2 = csr_src;
  const float* a3 = dinv; const float* a4 = bias; void* a5 = Hv;
  const float* a6 = Wout; const float* a7 = bout; float* a8 = Out; int a9 = n;
  void* args[] = {&a0, &a1, &a2, &a3, &a4, &a5, &a6, &a7, &a8, &a9};
  hipError_t err = hipLaunchCooperativeKernel(
      reinterpret_cast<void*>(agg_chunked_kernel<LPN, ROUNDS, MODE, true>),
      dim3(AGG_BLOCKS), dim3(256), args, 0, stream);
  if (err != hipSuccess) {
    (void)hipGetLastError();  // clear sticky error
    agg_chunked_kernel<LPN, ROUNDS, MODE, false><<<AGG_BLOCKS, 256, 0, stream>>>(
        Tq, rcp, csr_src, dinv, bias, Hv, Wout, bout, Out, n);
  }
}

extern "C" void kernel_launch(void* const* d_in, const int* in_sizes, int n_in,
                              void* d_out, int out_size, void* d_ws, size_t ws_size,
                              hipStream_t stream) {
  const float* x    = (const float*)d_in[0];
  const int*   ei   = (const int*)d_in[1];
  const float* W1   = (const float*)d_in[2];
  const float* b1   = (const float*)d_in[3];
  const float* W2   = (const float*)d_in[4];
  const float* b2   = (const float*)d_in[5];
  const float* W3   = (const float*)d_in[6];
  const float* b3   = (const float*)d_in[7];
  const float* Wout = (const float*)d_in[8];
  const float* bout = (const float*)d_in[9];

  const int n = NN, E = NE;
  const int* srcp = ei;
  const int* dstp = ei + E;

  char* ws = (char*)d_ws;
  int*    cntmat  = (int*)(ws + 0);            // 1,045,504 B
  int*    btotal  = (int*)(ws + 1045504);      // 4 KB
  int*    bbase   = (int*)(ws + 1049600);      // 4 KB
  int*    offmat  = (int*)(ws + 1053696);      // 1,045,504 B
  int*    rcp     = (int*)(ws + 2099200);      // 3.2 MB
  float*  dinv    = (float*)(ws + 5299200);    // 400 KB
  int*    csr_src = (int*)(ws + 5699216);      // 12.8 MB
  ushort* bufT    = (ushort*)(ws + 18499216);  // 25.6 MB bf16 [n,128]
  int*    store   = (int*)(ws + 18499216);     // 12.8 MB, aliases bufT (dead before gemm1)
  ushort* bufHb   = (ushort*)(ws + 44099216);  // 25.6 MB bf16 [n,128]

  float* outp = (float*)d_out;
  float* hemb = (float*)d_out + 2 * n;

  // ---- graph build ----
  pcount_kernel<<<NBLK, 256, 0, stream>>>(dstp, cntmat);
  rowsum_kernel<<<NB, 256, 0, stream>>>(cntmat, btotal);
  bucket_scan_kernel<<<1, 1024, 0, stream>>>(btotal, bbase);
  offsets_kernel<<<NB, 256, 0, stream>>>(cntmat, bbase, offmat);
  pscatter_kernel<<<NBLK, 256, 0, stream>>>(srcp, dstp, offmat, store);
  build_kernel<<<NB, 256, 0, stream>>>(btotal, bbase, store, rcp, dinv, csr_src);

  // ---- layer 1 ----
  gemm_kernel<128, false><<<dim3((n + 127) / 128, 2), 512, 0, stream>>>(x, W1, dinv, bufT, n);
  launch_agg<16, 13, 0>((const uint4*)bufT, rcp, csr_src, dinv, b1, (void*)bufHb,
                        nullptr, nullptr, nullptr, n, stream);

  // ---- layer 2 ----
  gemm_kernel<128, true><<<dim3((n + 127) / 128, 2), 512, 0, stream>>>(bufHb, W2, dinv, bufT, n);
  launch_agg<16, 13, 0>((const uint4*)bufT, rcp, csr_src, dinv, b2, (void*)bufHb,
                        nullptr, nullptr, nullptr, n, stream);

  // ---- layer 3 + fused output linear ----
  gemm_kernel<64, true><<<dim3((n + 127) / 128, 1), 512, 0, stream>>>(bufHb, W3, dinv, bufT, n);
  launch_agg<8, 7, 1>((const uint4*)bufT, rcp, csr_src, dinv, b3, (void*)hemb,
                      Wout, bout, outp, n, stream);
}